// Round 1
// baseline (143.075 us; speedup 1.0000x reference)
//
#include <hip/hip_runtime.h>
#include <hip/hip_bf16.h>

// Problem constants (MoEAggregator_455266533835)
#define B_SZ 2
#define S_SZ 2048
#define D_SZ 4096
#define N_ADP 8

// ---------------------------------------------------------------------------
// Kernel 1: gate = x[:, -1, :] @ gate_W^T + gate_b ; top-k -> 0/1 weight mask
// One block per batch. Writes w[b*8 + n] in {0.0, 1.0} to workspace.
// ---------------------------------------------------------------------------
__global__ void moe_gate_topk(const float* __restrict__ x,
                              const float* __restrict__ gate_W,
                              const float* __restrict__ gate_b,
                              const int* __restrict__ top_k_p,
                              float* __restrict__ w_out) {
    const int b = blockIdx.x;
    const float* xrow = x + ((size_t)b * S_SZ + (S_SZ - 1)) * D_SZ;

    float acc[N_ADP];
#pragma unroll
    for (int n = 0; n < N_ADP; ++n) acc[n] = 0.f;

    for (int d = threadIdx.x; d < D_SZ; d += blockDim.x) {
        const float xv = xrow[d];
#pragma unroll
        for (int n = 0; n < N_ADP; ++n)
            acc[n] += xv * gate_W[n * D_SZ + d];
    }

    // wave reduce (wave = 64)
#pragma unroll
    for (int n = 0; n < N_ADP; ++n) {
#pragma unroll
        for (int off = 32; off > 0; off >>= 1)
            acc[n] += __shfl_down(acc[n], off, 64);
    }

    __shared__ float red[N_ADP][4];  // up to 4 waves (256 threads)
    const int wave = threadIdx.x >> 6;
    const int lane = threadIdx.x & 63;
    if (lane == 0) {
#pragma unroll
        for (int n = 0; n < N_ADP; ++n) red[n][wave] = acc[n];
    }
    __syncthreads();

    if (threadIdx.x == 0) {
        const int nwaves = (int)(blockDim.x >> 6);
        float g[N_ADP];
#pragma unroll
        for (int n = 0; n < N_ADP; ++n) {
            float s = 0.f;
            for (int w = 0; w < nwaves; ++w) s += red[n][w];
            g[n] = s + gate_b[n];
        }
        float wsel[N_ADP];
#pragma unroll
        for (int n = 0; n < N_ADP; ++n) wsel[n] = 0.f;

        const int k = *top_k_p;
        for (int t = 0; t < k && t < N_ADP; ++t) {
            int best = -1;
            float bv = 0.f;
            for (int n = 0; n < N_ADP; ++n) {
                if (wsel[n] == 0.f && (best < 0 || g[n] > bv)) {
                    bv = g[n];
                    best = n;
                }
            }
            wsel[best] = 1.f;
        }
#pragma unroll
        for (int n = 0; n < N_ADP; ++n) w_out[b * N_ADP + n] = wsel[n];
    }
}

// ---------------------------------------------------------------------------
// Kernel 2: out[b,s,d] = base[b,s,d] + sum_n w[b,n] * lora[b,s,d,n]
// grid.y = batch; grid-stride over float4 groups of (S*D).
// Per group: 16B base + 128B lora reads, 16B write — fully coalesced.
// ---------------------------------------------------------------------------
__global__ void moe_aggregate(const float* __restrict__ base,
                              const float* __restrict__ lora,
                              const float* __restrict__ w_ws,
                              float* __restrict__ out) {
    const int b = blockIdx.y;

    // per-batch weights: wave-uniform loads, cached
    const float w0 = w_ws[b * N_ADP + 0];
    const float w1 = w_ws[b * N_ADP + 1];
    const float w2 = w_ws[b * N_ADP + 2];
    const float w3 = w_ws[b * N_ADP + 3];
    const float w4 = w_ws[b * N_ADP + 4];
    const float w5 = w_ws[b * N_ADP + 5];
    const float w6 = w_ws[b * N_ADP + 6];
    const float w7 = w_ws[b * N_ADP + 7];

    const size_t batch_elems = (size_t)S_SZ * D_SZ;
    const size_t batch_off = (size_t)b * batch_elems;
    const int ngroups = (int)(batch_elems / 4);

    const int stride = gridDim.x * blockDim.x;
    for (int g = blockIdx.x * blockDim.x + threadIdx.x; g < ngroups; g += stride) {
        const size_t e = batch_off + (size_t)g * 4;  // element index
        const float4 bv = *reinterpret_cast<const float4*>(base + e);
        const float4* lp = reinterpret_cast<const float4*>(lora + e * N_ADP);

        float4 ov;
        float* ovp = reinterpret_cast<float*>(&ov);
        const float* bvp = reinterpret_cast<const float*>(&bv);
#pragma unroll
        for (int j = 0; j < 4; ++j) {
            const float4 l0 = lp[2 * j];
            const float4 l1 = lp[2 * j + 1];
            float s = bvp[j];
            s += w0 * l0.x + w1 * l0.y + w2 * l0.z + w3 * l0.w;
            s += w4 * l1.x + w5 * l1.y + w6 * l1.z + w7 * l1.w;
            ovp[j] = s;
        }
        *reinterpret_cast<float4*>(out + e) = ov;
    }
}

extern "C" void kernel_launch(void* const* d_in, const int* in_sizes, int n_in,
                              void* d_out, int out_size, void* d_ws, size_t ws_size,
                              hipStream_t stream) {
    const float* x        = (const float*)d_in[0];
    const float* base_res = (const float*)d_in[1];
    const float* lora     = (const float*)d_in[2];
    const float* gate_W   = (const float*)d_in[3];
    const float* gate_b   = (const float*)d_in[4];
    const int*   top_k    = (const int*)d_in[5];
    float* out = (float*)d_out;
    float* w_ws = (float*)d_ws;  // B*N floats of 0/1 weights

    moe_gate_topk<<<dim3(B_SZ), dim3(256), 0, stream>>>(x, gate_W, gate_b, top_k, w_ws);

    dim3 grid(2048, B_SZ);
    moe_aggregate<<<grid, dim3(256), 0, stream>>>(base_res, lora, w_ws, out);
}

// Round 2
// 140.987 us; speedup vs baseline: 1.0148x; 1.0148x over previous
//
#include <hip/hip_runtime.h>
#include <hip/hip_bf16.h>

// Problem constants (MoEAggregator_455266533835)
#define B_SZ 2
#define S_SZ 2048
#define D_SZ 4096
#define N_ADP 8

// ---------------------------------------------------------------------------
// Kernel 1: gate = x[:, -1, :] @ gate_W^T + gate_b ; top-k -> 0/1 weight mask
// One block per batch (512 threads). Writes w[b*8+n] in {0,1} to workspace.
// ---------------------------------------------------------------------------
__global__ void moe_gate_topk(const float* __restrict__ x,
                              const float* __restrict__ gate_W,
                              const float* __restrict__ gate_b,
                              const int* __restrict__ top_k_p,
                              float* __restrict__ w_out) {
    const int b = blockIdx.x;
    const float* xrow = x + ((size_t)b * S_SZ + (S_SZ - 1)) * D_SZ;

    float acc[N_ADP];
#pragma unroll
    for (int n = 0; n < N_ADP; ++n) acc[n] = 0.f;

#pragma unroll 4
    for (int d = threadIdx.x; d < D_SZ; d += blockDim.x) {
        const float xv = xrow[d];
#pragma unroll
        for (int n = 0; n < N_ADP; ++n)
            acc[n] += xv * gate_W[n * D_SZ + d];
    }

    // wave reduce (wave = 64)
#pragma unroll
    for (int n = 0; n < N_ADP; ++n) {
#pragma unroll
        for (int off = 32; off > 0; off >>= 1)
            acc[n] += __shfl_down(acc[n], off, 64);
    }

    __shared__ float red[N_ADP][8];  // up to 8 waves (512 threads)
    const int wave = threadIdx.x >> 6;
    const int lane = threadIdx.x & 63;
    if (lane == 0) {
#pragma unroll
        for (int n = 0; n < N_ADP; ++n) red[n][wave] = acc[n];
    }
    __syncthreads();

    if (threadIdx.x == 0) {
        const int nwaves = (int)(blockDim.x >> 6);
        float g[N_ADP];
#pragma unroll
        for (int n = 0; n < N_ADP; ++n) {
            float s = 0.f;
            for (int w = 0; w < nwaves; ++w) s += red[n][w];
            g[n] = s + gate_b[n];
        }
        float wsel[N_ADP];
#pragma unroll
        for (int n = 0; n < N_ADP; ++n) wsel[n] = 0.f;

        const int k = *top_k_p;
        for (int t = 0; t < k && t < N_ADP; ++t) {
            int best = -1;
            float bv = 0.f;
            for (int n = 0; n < N_ADP; ++n) {
                if (wsel[n] == 0.f && (best < 0 || g[n] > bv)) {
                    bv = g[n];
                    best = n;
                }
            }
            wsel[best] = 1.f;
        }
#pragma unroll
        for (int n = 0; n < N_ADP; ++n) w_out[b * N_ADP + n] = wsel[n];
    }
}

// ---------------------------------------------------------------------------
// Kernel 2: out[b,s,d] = base[b,s,d] + sum_n w[b,n] * lora[b,s,d,n]
//
// Wave-tile = 512 consecutive lora float4s (8 KiB) = 64 output float4s.
// Phase 1: 8 lane-contiguous global float4 loads (1 KiB per instruction).
// Phase 2: stage into wave-private LDS region with XOR swizzle
//          slot' = slot ^ ((slot>>3)&7)  -- involution, spreads the
//          128-B-stride readback over all 8 bank-groups (8 lanes per
//          4-bank group = minimum aliasing for wave64, i.e. free).
// Phase 3: each lane reads its 8 owner quads (lora quads 8l..8l+7),
//          weighted-sums with the 0/1 mask, adds base, coalesced store.
// No __syncthreads needed: each wave touches only its own LDS region and
// the compiler orders same-wave ds_write->ds_read via lgkmcnt.
// ---------------------------------------------------------------------------
__global__ __launch_bounds__(256) void moe_aggregate(
        const float4* __restrict__ base4,
        const float4* __restrict__ lora4,
        const float* __restrict__ w_ws,
        float4* __restrict__ out4) {
    __shared__ float4 lds[4][512];  // 32 KiB: one 512-quad tile per wave

    const int wv = threadIdx.x >> 6;
    const int lane = threadIdx.x & 63;
    const int b = blockIdx.y;

    const float* wp = w_ws + b * N_ADP;
    const float w0 = wp[0], w1 = wp[1], w2 = wp[2], w3 = wp[3];
    const float w4 = wp[4], w5 = wp[5], w6 = wp[6], w7 = wp[7];

    const size_t loraq_batch = (size_t)S_SZ * D_SZ * (N_ADP / 4);  // 16M quads
    const size_t outq_batch  = (size_t)S_SZ * D_SZ / 4;            // 2M quads
    const float4* lbase = lora4 + (size_t)b * loraq_batch;
    const float4* bbase = base4 + (size_t)b * outq_batch;
    float4*       obase = out4  + (size_t)b * outq_batch;

    const int tiles   = (int)(loraq_batch / 512);  // 32768
    const int wstride = gridDim.x * 4;

    for (int t = blockIdx.x * 4 + wv; t < tiles; t += wstride) {
        const size_t qbase = (size_t)t * 512;

        // Phase 1: coalesced global loads
        float4 v[8];
#pragma unroll
        for (int r = 0; r < 8; ++r)
            v[r] = lbase[qbase + (size_t)r * 64 + lane];

        // Phase 2: swizzled LDS write (slot = r*64+lane; (slot>>3)&7 = (lane>>3)&7)
#pragma unroll
        for (int r = 0; r < 8; ++r)
            lds[wv][(r * 64 + lane) ^ ((lane >> 3) & 7)] = v[r];

        // Phase 3: owner read + combine + store
        const size_t o = qbase / 8 + lane;
        const float4 bv = bbase[o];

        float4 q[8];
#pragma unroll
        for (int j = 0; j < 8; ++j)
            q[j] = lds[wv][(8 * lane + j) ^ (lane & 7)];

        float4 ov;
        ov.x = bv.x + w0 * q[0].x + w1 * q[0].y + w2 * q[0].z + w3 * q[0].w
                    + w4 * q[1].x + w5 * q[1].y + w6 * q[1].z + w7 * q[1].w;
        ov.y = bv.y + w0 * q[2].x + w1 * q[2].y + w2 * q[2].z + w3 * q[2].w
                    + w4 * q[3].x + w5 * q[3].y + w6 * q[3].z + w7 * q[3].w;
        ov.z = bv.z + w0 * q[4].x + w1 * q[4].y + w2 * q[4].z + w3 * q[4].w
                    + w4 * q[5].x + w5 * q[5].y + w6 * q[5].z + w7 * q[5].w;
        ov.w = bv.w + w0 * q[6].x + w1 * q[6].y + w2 * q[6].z + w3 * q[6].w
                    + w4 * q[7].x + w5 * q[7].y + w6 * q[7].z + w7 * q[7].w;
        obase[o] = ov;
    }
}

extern "C" void kernel_launch(void* const* d_in, const int* in_sizes, int n_in,
                              void* d_out, int out_size, void* d_ws, size_t ws_size,
                              hipStream_t stream) {
    const float* x        = (const float*)d_in[0];
    const float* base_res = (const float*)d_in[1];
    const float* lora     = (const float*)d_in[2];
    const float* gate_W   = (const float*)d_in[3];
    const float* gate_b   = (const float*)d_in[4];
    const int*   top_k    = (const int*)d_in[5];
    float* out  = (float*)d_out;
    float* w_ws = (float*)d_ws;  // B*N floats of 0/1 weights

    moe_gate_topk<<<dim3(B_SZ), dim3(512), 0, stream>>>(x, gate_W, gate_b, top_k, w_ws);

    dim3 grid(512, B_SZ);
    moe_aggregate<<<grid, dim3(256), 0, stream>>>(
        (const float4*)base_res, (const float4*)lora, w_ws, (float4*)out);
}